// Round 10
// baseline (20.706 us; speedup 1.0000x reference)
//
#include <hip/hip_runtime.h>
#include <hip/hip_bf16.h>

#define NNODE 62
#define FIN 5
#define HID 400
#define HIDP 416        // 13 tiles of 32 cols (pad cols zero)
#define WST 72          // XT row stride in shorts (144B)
#define WAVES 8         // 512-thread block, 1 graph per wave, 2 blocks/CU

typedef __attribute__((ext_vector_type(8)))  short bf16x8;
typedef __attribute__((ext_vector_type(4)))  float f32x4;
typedef __attribute__((ext_vector_type(8)))  float f32x8;
typedef __attribute__((ext_vector_type(2)))  float f32x2;
typedef __attribute__((ext_vector_type(16))) float f32x16;

static __device__ __forceinline__ short f2bf(float x) {
    __hip_bfloat16 h = __float2bfloat16(x);
    return *reinterpret_cast<short*>(&h);
}

// lower-tri closed-form index: W[r][c] = ew[hi*(hi+1)/2 + lo]
static __device__ __forceinline__ int tridx(int r, int c) {
    const int hi = r > c ? r : c;
    const int lo = r > c ? c : r;
    return (hi * (hi + 1)) / 2 + lo;
}

// relu + horizontal sum of a 32x32 MFMA accumulator (16 f32/lane).
static __device__ __forceinline__ float hsum16_relu(f32x16 d) {
    const f32x16 z = {};
    const f32x16 r = __builtin_elementwise_max(d, z);
    const f32x8 a = __builtin_shufflevector(r, r, 0,1,2,3,4,5,6,7)
                  + __builtin_shufflevector(r, r, 8,9,10,11,12,13,14,15);
    const f32x4 b = __builtin_shufflevector(a, a, 0,1,2,3)
                  + __builtin_shufflevector(a, a, 4,5,6,7);
    const f32x2 c = __builtin_shufflevector(b, b, 0,1)
                  + __builtin_shufflevector(b, b, 2,3);
    return c[0] + c[1];
}

// 512 blocks x 512 threads (8 waves) = 2 blocks/CU: one block's setup/barriers
// overlap the other block's compute. No dense W is ever materialized — degrees
// and normalized A-fragments gather straight from the tril parameter array.
__global__ __launch_bounds__(512, 4) void rgnn_fused(
        const float* __restrict__ X,     const float* __restrict__ ew,
        const float* __restrict__ lin_w, const float* __restrict__ lin_b,
        const float* __restrict__ fc_w,  const float* __restrict__ fc_b,
        float* __restrict__ out, int B) {
    __shared__ float dinv[64];
    __shared__ __align__(16) short Wfrag[8][64][8];     // 8192 B: 16x16 A-frag order
    __shared__ __align__(16) short lwT[HIDP][8];        // 6656 B: [col][k], k=5 = bias
    __shared__ float fcs[HIDP * 2];                     // 3328 B
    __shared__ __align__(16) short XT[WAVES][FIN][WST]; // 5760 B: X^T then Y1^T
    __shared__ __align__(16) short Y2A[WAVES][64][8];   // 8192 B: lin A rows
    __shared__ __align__(16) short Zs[8];               // ~32 KB total

    const int t = threadIdx.x;
    const int w = t >> 6;
    const int lane = t & 63;
    const int b = blockIdx.x * WAVES + w;

    const int f16 = lane & 15;
    const int g   = lane >> 4;
    const bool fr = (f16 < FIN);

    // ---- phase 0: stage weights; degrees straight from ew; load X ----
    for (int i = t; i < HIDP * 8; i += 512) {
        const int c = i >> 3, k = i & 7;
        float v = 0.f;
        if (c < HID) {
            if (k < FIN) v = lin_w[k * HID + c];
            else if (k == FIN) v = lin_b[c];
        }
        lwT[c][k] = f2bf(v);
    }
    for (int i = t; i < HIDP * 2; i += 512) fcs[i] = (i < HID * 2) ? fc_w[i] : 0.f;
    if (t < 8) Zs[t] = 0;
    if (t < NNODE * 8) {          // deg[r] = sum_c |W[r,c]|, 8 threads/row
        const int r = t >> 3, j = t & 7;
        float s = 0.f;
        for (int c = j; c < NNODE; c += 8) s += fabsf(ew[tridx(r, c)]);
        s += __shfl_xor(s, 4);
        s += __shfl_xor(s, 2);
        s += __shfl_xor(s, 1);
        if (j == 0) dinv[r] = (s > 0.f) ? (1.0f / sqrtf(s)) : 0.f;
    }
    bf16x8 bx0 = {}, bx1 = {};
    if (b < B) {
        const float* xb = X + (size_t)b * (NNODE * FIN);
        for (int idx = lane; idx < NNODE * FIN; idx += 64) {
            const int n = idx / FIN, f = idx - n * FIN;
            XT[w][f][n] = f2bf(xb[idx]);
        }
        if (lane < FIN) *(unsigned int*)&XT[w][lane][62] = 0u;   // node pads 62,63
        // EARLY hop-1 B-frag load: same-wave RAW on XT is in-order (no barrier
        // needed); masked lanes keep a register zero.
        const int fc16 = fr ? f16 : 0;
        const bf16x8 e0 = *(const bf16x8*)&XT[w][fc16][g * 8];
        const bf16x8 e1 = *(const bf16x8*)&XT[w][fc16][32 + g * 8];
        if (fr) { bx0 = e0; bx1 = e1; }
    }
    __syncthreads();

    // ---- phase 1: normalized bf16 A-frags gathered from ew (all 512 threads) ----
    {
        const int fi = t >> 6, l = t & 63;           // fi = rt*2 + ks
        const int rt = fi >> 1, ks = fi & 1;
        const int row = (l & 15) + 16 * rt;
        const int k0 = ks * 32 + (l >> 4) * 8;
        union { short s[8]; bf16x8 v8; } u;
        #pragma unroll
        for (int j = 0; j < 8; ++j) {
            const int k = k0 + j;
            u.s[j] = (row < NNODE && k < NNODE)
                   ? f2bf(ew[tridx(row, k)] * dinv[row] * dinv[k]) : (short)0;
        }
        *(bf16x8*)&Wfrag[fi][l][0] = u.v8;
    }
    __syncthreads();    // last block-wide barrier

    if (b >= B) return;

    // ---- per-wave: cache W A-frags in VGPRs ----
    bf16x8 wf[8];
    #pragma unroll
    for (int fi = 0; fi < 8; ++fi) wf[fi] = *(const bf16x8*)&Wfrag[fi][lane][0];

    const short* zp = &Zs[0];
    const f32x4 z4 = {0.f, 0.f, 0.f, 0.f};

    // hop 1: Y1 = Wn @ X  (bx0/bx1 loaded pre-barrier)
    f32x4 acc[4];
    __builtin_amdgcn_s_setprio(1);
    #pragma unroll
    for (int rt = 0; rt < 4; ++rt) {
        acc[rt] = __builtin_amdgcn_mfma_f32_16x16x32_bf16(wf[rt * 2 + 0], bx0, z4, 0, 0, 0);
        acc[rt] = __builtin_amdgcn_mfma_f32_16x16x32_bf16(wf[rt * 2 + 1], bx1, acc[rt], 0, 0, 0);
    }
    __builtin_amdgcn_s_setprio(0);
    if (fr) {   // Y1^T writeback (same-wave in-order LDS)
        #pragma unroll
        for (int rt = 0; rt < 4; ++rt) {
            const int n0 = rt * 16 + g * 4;          // D row = (lane>>4)*4 + reg (+16rt)
            const unsigned int d0 = (unsigned short)f2bf(acc[rt][0]) |
                                    ((unsigned int)(unsigned short)f2bf(acc[rt][1]) << 16);
            const unsigned int d1 = (unsigned short)f2bf(acc[rt][2]) |
                                    ((unsigned int)(unsigned short)f2bf(acc[rt][3]) << 16);
            if (n0 + 1 < NNODE) *(unsigned int*)&XT[w][f16][n0] = d0;
            if (n0 + 3 < NNODE) *(unsigned int*)&XT[w][f16][n0 + 2] = d1;
        }
    }

    // hop 2: Y2 = Wn @ Y1
    {
        const short* p0 = fr ? &XT[w][f16][g * 8]      : zp;
        const short* p1 = fr ? &XT[w][f16][32 + g * 8] : zp;
        bx0 = *(const bf16x8*)p0;
        bx1 = *(const bf16x8*)p1;
    }
    __builtin_amdgcn_s_setprio(1);
    #pragma unroll
    for (int rt = 0; rt < 4; ++rt) {
        acc[rt] = __builtin_amdgcn_mfma_f32_16x16x32_bf16(wf[rt * 2 + 0], bx0, z4, 0, 0, 0);
        acc[rt] = __builtin_amdgcn_mfma_f32_16x16x32_bf16(wf[rt * 2 + 1], bx1, acc[rt], 0, 0, 0);
    }
    __builtin_amdgcn_s_setprio(0);
    // scatter Y2 with FULL Y2A coverage: lanes f16<8 write k=0..7
    if (f16 < 8) {
        #pragma unroll
        for (int rt = 0; rt < 4; ++rt) {
            const int n0 = rt * 16 + g * 4;
            #pragma unroll
            for (int r = 0; r < 4; ++r) {
                const int n = n0 + r;
                short val = 0;
                if (n < NNODE) {
                    val = (f16 < FIN) ? f2bf(acc[rt][r])
                                      : ((f16 == FIN) ? (short)0x3F80 : (short)0);
                }
                Y2A[w][n][f16] = val;
            }
        }
    }

    // ---- lin stage (32x32x16): A rows = Y2A nodes; lanes 0-31 carry k=0..7 ----
    const int r32 = lane & 31;
    const bool alo = (lane < 32);
    bf16x8 af0, af1;
    {
        const short* a0 = alo ? &Y2A[w][r32][0]      : zp;
        const short* a1 = alo ? &Y2A[w][32 + r32][0] : zp;
        af0 = *(const bf16x8*)a0;
        af1 = *(const bf16x8*)a1;
    }

    // 13 col-tiles, 2-deep software pipeline (issue ct+1's MFMAs before
    // reducing ct; indices all compile-time via full unroll).
    const f32x16 z16 = {};
    float o0 = 0.f, o1 = 0.f;
    bf16x8 bfr[2];
    float2 fw[2];
    f32x16 da[2], db[2];
    {
        const short* bp = alo ? &lwT[r32][0] : zp;
        bfr[0] = *(const bf16x8*)bp;
        fw[0]  = *(const float2*)&fcs[r32 * 2];
    }
    __builtin_amdgcn_s_setprio(1);
    da[0] = __builtin_amdgcn_mfma_f32_32x32x16_bf16(af0, bfr[0], z16, 0, 0, 0);
    db[0] = __builtin_amdgcn_mfma_f32_32x32x16_bf16(af1, bfr[0], z16, 0, 0, 0);
    __builtin_amdgcn_s_setprio(0);
    #pragma unroll
    for (int ct = 0; ct < 13; ++ct) {
        const int cur = ct & 1, nxt = cur ^ 1;
        if (ct < 12) {
            const short* bp = alo ? &lwT[32 * (ct + 1) + r32][0] : zp;
            bfr[nxt] = *(const bf16x8*)bp;
            fw[nxt]  = *(const float2*)&fcs[(32 * (ct + 1) + r32) * 2];
            __builtin_amdgcn_s_setprio(1);
            da[nxt] = __builtin_amdgcn_mfma_f32_32x32x16_bf16(af0, bfr[nxt], z16, 0, 0, 0);
            db[nxt] = __builtin_amdgcn_mfma_f32_32x32x16_bf16(af1, bfr[nxt], z16, 0, 0, 0);
            __builtin_amdgcn_s_setprio(0);
        }
        const float pc = hsum16_relu(da[cur]) + hsum16_relu(db[cur]);
        o0 = fmaf(pc, fw[cur].x, o0);
        o1 = fmaf(pc, fw[cur].y, o1);
    }

    // one full-wave butterfly over (row-half, col) partials
    #pragma unroll
    for (int s = 32; s > 0; s >>= 1) {
        o0 += __shfl_xor(o0, s, 64);
        o1 += __shfl_xor(o1, s, 64);
    }
    if (lane == 0) {
        out[2 * b + 0] = o0 + fc_b[0];
        out[2 * b + 1] = o1 + fc_b[1];
    }
}

extern "C" void kernel_launch(void* const* d_in, const int* in_sizes, int n_in,
                              void* d_out, int out_size, void* d_ws, size_t ws_size,
                              hipStream_t stream) {
    const float* X     = (const float*)d_in[0];
    const float* ew    = (const float*)d_in[2];
    const float* lin_w = (const float*)d_in[3];
    const float* lin_b = (const float*)d_in[4];
    const float* fc_w  = (const float*)d_in[5];
    const float* fc_b  = (const float*)d_in[6];

    float* outp = (float*)d_out;
    const int B = in_sizes[0] / (NNODE * FIN);   // 4096

    rgnn_fused<<<(B + WAVES - 1) / WAVES, 512, 0, stream>>>(
        X, ew, lin_w, lin_b, fc_w, fc_b, outp, B);
}

// Round 11
// 19.922 us; speedup vs baseline: 1.0393x; 1.0393x over previous
//
#include <hip/hip_runtime.h>
#include <hip/hip_bf16.h>

#define NNODE 62
#define FIN 5
#define HID 400
#define HIDP 416        // 13 tiles of 32 cols (pad cols zero)
#define WST 72          // XT row stride in shorts (144B)
#define WAVES 16        // 1024-thread block, 1 graph per wave, 1 block/CU

typedef __attribute__((ext_vector_type(8)))  short bf16x8;
typedef __attribute__((ext_vector_type(4)))  float f32x4;
typedef __attribute__((ext_vector_type(8)))  float f32x8;
typedef __attribute__((ext_vector_type(2)))  float f32x2;
typedef __attribute__((ext_vector_type(16))) float f32x16;

static __device__ __forceinline__ short f2bf(float x) {
    __hip_bfloat16 h = __float2bfloat16(x);
    return *reinterpret_cast<short*>(&h);
}

// lower-tri closed-form index: W[r][c] = ew[hi*(hi+1)/2 + lo]
static __device__ __forceinline__ int tridx(int r, int c) {
    const int hi = r > c ? r : c;
    const int lo = r > c ? c : r;
    return (hi * (hi + 1)) / 2 + lo;
}

// relu + horizontal sum of a 32x32 MFMA accumulator (16 f32/lane).
static __device__ __forceinline__ float hsum16_relu(f32x16 d) {
    const f32x16 z = {};
    const f32x16 r = __builtin_elementwise_max(d, z);
    const f32x8 a = __builtin_shufflevector(r, r, 0,1,2,3,4,5,6,7)
                  + __builtin_shufflevector(r, r, 8,9,10,11,12,13,14,15);
    const f32x4 b = __builtin_shufflevector(a, a, 0,1,2,3)
                  + __builtin_shufflevector(a, a, 4,5,6,7);
    const f32x2 c = __builtin_shufflevector(b, b, 0,1)
                  + __builtin_shufflevector(b, b, 2,3);
    return c[0] + c[1];
}

// 256 blocks x 1024 threads (16 waves) = 1 block/CU, 4 waves/SIMD (R9 config).
// No dense W materialized: degrees and normalized A-frags gather straight from
// the 7.8 KB tril array (L1-resident after the degree pass). Two barriers.
__global__ __launch_bounds__(1024, 4) void rgnn_fused(
        const float* __restrict__ X,     const float* __restrict__ ew,
        const float* __restrict__ lin_w, const float* __restrict__ lin_b,
        const float* __restrict__ fc_w,  const float* __restrict__ fc_b,
        float* __restrict__ out, int B) {
    __shared__ float dinv[64];
    __shared__ __align__(16) short Wfrag[8][64][8];     // 8192 B: 16x16 A-frag order
    __shared__ __align__(16) short lwT[HIDP][8];        // 6656 B: [col][k], k=5 = bias
    __shared__ float fcs[HIDP * 2];                     // 3328 B
    __shared__ __align__(16) short XT[WAVES][FIN][WST]; // 11520 B: X^T then Y1^T
    __shared__ __align__(16) short Y2A[WAVES][64][8];   // 16384 B: lin A rows
    __shared__ __align__(16) short Zs[8];               // ~46 KB total

    const int t = threadIdx.x;
    const int w = t >> 6;
    const int lane = t & 63;
    const int b = blockIdx.x * WAVES + w;

    const int f16 = lane & 15;
    const int g   = lane >> 4;
    const bool fr = (f16 < FIN);

    // ---- phase 0 (one barrier region): lwT/fcs staging, deg from ew, X load ----
    for (int i = t; i < HIDP * 8; i += 1024) {
        const int c = i >> 3, k = i & 7;
        float v = 0.f;
        if (c < HID) {
            if (k < FIN) v = lin_w[k * HID + c];
            else if (k == FIN) v = lin_b[c];
        }
        lwT[c][k] = f2bf(v);
    }
    for (int i = t; i < HIDP * 2; i += 1024) fcs[i] = (i < HID * 2) ? fc_w[i] : 0.f;
    if (t < 8) Zs[t] = 0;
    if (t < NNODE * 8) {          // deg[r] = sum_c |W[r,c]|, 8 threads/row
        const int r = t >> 3, j = t & 7;
        float s = 0.f;
        for (int c = j; c < NNODE; c += 8) s += fabsf(ew[tridx(r, c)]);
        s += __shfl_xor(s, 4);
        s += __shfl_xor(s, 2);
        s += __shfl_xor(s, 1);
        if (j == 0) dinv[r] = (s > 0.f) ? (1.0f / sqrtf(s)) : 0.f;
    }
    bf16x8 bx0 = {}, bx1 = {};
    if (b < B) {
        const float* xb = X + (size_t)b * (NNODE * FIN);
        for (int idx = lane; idx < NNODE * FIN; idx += 64) {
            const int n = idx / FIN, f = idx - n * FIN;
            XT[w][f][n] = f2bf(xb[idx]);
        }
        if (lane < FIN) *(unsigned int*)&XT[w][lane][62] = 0u;   // node pads 62,63
        // EARLY hop-1 B-frag load: same-wave RAW on XT is in-order (no barrier
        // needed); masked lanes keep a register zero.
        const int fc16 = fr ? f16 : 0;
        const bf16x8 e0 = *(const bf16x8*)&XT[w][fc16][g * 8];
        const bf16x8 e1 = *(const bf16x8*)&XT[w][fc16][32 + g * 8];
        if (fr) { bx0 = e0; bx1 = e1; }
    }
    __syncthreads();

    // ---- phase 1: normalized bf16 A-frags gathered from ew (threads 0-511) ----
    if (t < 512) {
        const int fi = t >> 6, l = t & 63;           // fi = rt*2 + ks
        const int rt = fi >> 1, ks = fi & 1;
        const int row = (l & 15) + 16 * rt;
        const int k0 = ks * 32 + (l >> 4) * 8;
        union { short s[8]; bf16x8 v8; } u;
        #pragma unroll
        for (int j = 0; j < 8; ++j) {
            const int k = k0 + j;
            u.s[j] = (row < NNODE && k < NNODE)
                   ? f2bf(ew[tridx(row, k)] * dinv[row] * dinv[k]) : (short)0;
        }
        *(bf16x8*)&Wfrag[fi][l][0] = u.v8;
    }
    __syncthreads();    // last block-wide barrier

    if (b >= B) return;

    // ---- per-wave: cache W A-frags in VGPRs ----
    bf16x8 wf[8];
    #pragma unroll
    for (int fi = 0; fi < 8; ++fi) wf[fi] = *(const bf16x8*)&Wfrag[fi][lane][0];

    const short* zp = &Zs[0];
    const f32x4 z4 = {0.f, 0.f, 0.f, 0.f};

    // hop 1: Y1 = Wn @ X  (bx0/bx1 loaded pre-barrier)
    f32x4 acc[4];
    __builtin_amdgcn_s_setprio(1);
    #pragma unroll
    for (int rt = 0; rt < 4; ++rt) {
        acc[rt] = __builtin_amdgcn_mfma_f32_16x16x32_bf16(wf[rt * 2 + 0], bx0, z4, 0, 0, 0);
        acc[rt] = __builtin_amdgcn_mfma_f32_16x16x32_bf16(wf[rt * 2 + 1], bx1, acc[rt], 0, 0, 0);
    }
    __builtin_amdgcn_s_setprio(0);
    if (fr) {   // Y1^T writeback (same-wave in-order LDS)
        #pragma unroll
        for (int rt = 0; rt < 4; ++rt) {
            const int n0 = rt * 16 + g * 4;          // D row = (lane>>4)*4 + reg (+16rt)
            const unsigned int d0 = (unsigned short)f2bf(acc[rt][0]) |
                                    ((unsigned int)(unsigned short)f2bf(acc[rt][1]) << 16);
            const unsigned int d1 = (unsigned short)f2bf(acc[rt][2]) |
                                    ((unsigned int)(unsigned short)f2bf(acc[rt][3]) << 16);
            if (n0 + 1 < NNODE) *(unsigned int*)&XT[w][f16][n0] = d0;
            if (n0 + 3 < NNODE) *(unsigned int*)&XT[w][f16][n0 + 2] = d1;
        }
    }

    // hop 2: Y2 = Wn @ Y1
    {
        const short* p0 = fr ? &XT[w][f16][g * 8]      : zp;
        const short* p1 = fr ? &XT[w][f16][32 + g * 8] : zp;
        bx0 = *(const bf16x8*)p0;
        bx1 = *(const bf16x8*)p1;
    }
    __builtin_amdgcn_s_setprio(1);
    #pragma unroll
    for (int rt = 0; rt < 4; ++rt) {
        acc[rt] = __builtin_amdgcn_mfma_f32_16x16x32_bf16(wf[rt * 2 + 0], bx0, z4, 0, 0, 0);
        acc[rt] = __builtin_amdgcn_mfma_f32_16x16x32_bf16(wf[rt * 2 + 1], bx1, acc[rt], 0, 0, 0);
    }
    __builtin_amdgcn_s_setprio(0);
    // scatter Y2 with FULL Y2A coverage: lanes f16<8 write k=0..7
    if (f16 < 8) {
        #pragma unroll
        for (int rt = 0; rt < 4; ++rt) {
            const int n0 = rt * 16 + g * 4;
            #pragma unroll
            for (int r = 0; r < 4; ++r) {
                const int n = n0 + r;
                short val = 0;
                if (n < NNODE) {
                    val = (f16 < FIN) ? f2bf(acc[rt][r])
                                      : ((f16 == FIN) ? (short)0x3F80 : (short)0);
                }
                Y2A[w][n][f16] = val;
            }
        }
    }

    // ---- lin stage (32x32x16): A rows = Y2A nodes; lanes 0-31 carry k=0..7 ----
    const int r32 = lane & 31;
    const bool alo = (lane < 32);
    bf16x8 af0, af1;
    {
        const short* a0 = alo ? &Y2A[w][r32][0]      : zp;
        const short* a1 = alo ? &Y2A[w][32 + r32][0] : zp;
        af0 = *(const bf16x8*)a0;
        af1 = *(const bf16x8*)a1;
    }

    // 13 col-tiles, 2-deep software pipeline (issue ct+1's MFMAs before
    // reducing ct; indices all compile-time via full unroll).
    const f32x16 z16 = {};
    float o0 = 0.f, o1 = 0.f;
    bf16x8 bfr[2];
    float2 fw[2];
    f32x16 da[2], db[2];
    {
        const short* bp = alo ? &lwT[r32][0] : zp;
        bfr[0] = *(const bf16x8*)bp;
        fw[0]  = *(const float2*)&fcs[r32 * 2];
    }
    __builtin_amdgcn_s_setprio(1);
    da[0] = __builtin_amdgcn_mfma_f32_32x32x16_bf16(af0, bfr[0], z16, 0, 0, 0);
    db[0] = __builtin_amdgcn_mfma_f32_32x32x16_bf16(af1, bfr[0], z16, 0, 0, 0);
    __builtin_amdgcn_s_setprio(0);
    #pragma unroll
    for (int ct = 0; ct < 13; ++ct) {
        const int cur = ct & 1, nxt = cur ^ 1;
        if (ct < 12) {
            const short* bp = alo ? &lwT[32 * (ct + 1) + r32][0] : zp;
            bfr[nxt] = *(const bf16x8*)bp;
            fw[nxt]  = *(const float2*)&fcs[(32 * (ct + 1) + r32) * 2];
            __builtin_amdgcn_s_setprio(1);
            da[nxt] = __builtin_amdgcn_mfma_f32_32x32x16_bf16(af0, bfr[nxt], z16, 0, 0, 0);
            db[nxt] = __builtin_amdgcn_mfma_f32_32x32x16_bf16(af1, bfr[nxt], z16, 0, 0, 0);
            __builtin_amdgcn_s_setprio(0);
        }
        const float pc = hsum16_relu(da[cur]) + hsum16_relu(db[cur]);
        o0 = fmaf(pc, fw[cur].x, o0);
        o1 = fmaf(pc, fw[cur].y, o1);
    }

    // one full-wave butterfly over (row-half, col) partials
    #pragma unroll
    for (int s = 32; s > 0; s >>= 1) {
        o0 += __shfl_xor(o0, s, 64);
        o1 += __shfl_xor(o1, s, 64);
    }
    if (lane == 0) {
        out[2 * b + 0] = o0 + fc_b[0];
        out[2 * b + 1] = o1 + fc_b[1];
    }
}

extern "C" void kernel_launch(void* const* d_in, const int* in_sizes, int n_in,
                              void* d_out, int out_size, void* d_ws, size_t ws_size,
                              hipStream_t stream) {
    const float* X     = (const float*)d_in[0];
    const float* ew    = (const float*)d_in[2];
    const float* lin_w = (const float*)d_in[3];
    const float* lin_b = (const float*)d_in[4];
    const float* fc_w  = (const float*)d_in[5];
    const float* fc_b  = (const float*)d_in[6];

    float* outp = (float*)d_out;
    const int B = in_sizes[0] / (NNODE * FIN);   // 4096

    rgnn_fused<<<(B + WAVES - 1) / WAVES, 1024, 0, stream>>>(
        X, ew, lin_w, lin_b, fc_w, fc_b, outp, B);
}

// Round 12
// 19.189 us; speedup vs baseline: 1.0790x; 1.0382x over previous
//
#include <hip/hip_runtime.h>
#include <hip/hip_bf16.h>

#define NNODE 62
#define FIN 5
#define HID 400
#define HIDP 416        // 13 tiles of 32 cols (pad cols zero)
#define NTRIL 1953
#define MST 63          // f32 Wn row stride
#define WST 72          // XT row stride in shorts (144B)
#define WAVES 16        // 1024-thread block, 1 graph per wave, 1 block per CU

typedef __attribute__((ext_vector_type(8)))  short bf16x8;
typedef __attribute__((ext_vector_type(4)))  float f32x4;
typedef __attribute__((ext_vector_type(8)))  float f32x8;
typedef __attribute__((ext_vector_type(2)))  float f32x2;
typedef __attribute__((ext_vector_type(16))) float f32x16;

static __device__ __forceinline__ short f2bf(float x) {
    __hip_bfloat16 h = __float2bfloat16(x);
    return *reinterpret_cast<short*>(&h);
}

// relu + horizontal sum of a 32x32 MFMA accumulator (16 f32/lane).
static __device__ __forceinline__ float hsum16_relu(f32x16 d) {
    const f32x16 z = {};
    const f32x16 r = __builtin_elementwise_max(d, z);
    const f32x8 a = __builtin_shufflevector(r, r, 0,1,2,3,4,5,6,7)
                  + __builtin_shufflevector(r, r, 8,9,10,11,12,13,14,15);
    const f32x4 b = __builtin_shufflevector(a, a, 0,1,2,3)
                  + __builtin_shufflevector(a, a, 4,5,6,7);
    const f32x2 c = __builtin_shufflevector(b, b, 0,1)
                  + __builtin_shufflevector(b, b, 2,3);
    return c[0] + c[1];
}

// 256 blocks x 1024 threads (16 waves) = 1 block/CU, 4 waves/SIMD.
// Block builds Wn/Wfrag/lwT once; each wave computes one graph:
//   hops (16x16x32, W-frags in VGPRs) -> lin (32x32x16, 13 tiles,
//   2-deep software pipeline) -> fused relu-pool + fc, one butterfly.
__global__ __launch_bounds__(1024, 4) void rgnn_fused(
        const float* __restrict__ X,     const float* __restrict__ ew,
        const int* __restrict__ tx,      const int* __restrict__ ty,
        const float* __restrict__ lin_w, const float* __restrict__ lin_b,
        const float* __restrict__ fc_w,  const float* __restrict__ fc_b,
        float* __restrict__ out, int B) {
    __shared__ float Wn[NNODE * MST];                   // 15624 B
    __shared__ float dinv[64];
    __shared__ __align__(16) short Wfrag[8][64][8];     // 8192 B: 16x16 A-frag order
    __shared__ __align__(16) short lwT[HIDP][8];        // 6656 B: [col][k], k=5 = bias
    __shared__ float fcs[HIDP * 2];                     // 3328 B
    __shared__ __align__(16) short XT[WAVES][FIN][WST]; // 11520 B: X^T then Y1^T
    __shared__ __align__(16) short Y2A[WAVES][64][8];   // 16384 B: lin A rows
    __shared__ __align__(16) short Zs[8];               // ~62 KB total

    const int t = threadIdx.x;
    const int w = t >> 6;
    const int lane = t & 63;
    const int b = blockIdx.x * WAVES + w;

    const int f16 = lane & 15;
    const int g   = lane >> 4;
    const bool fr = (f16 < FIN);

    // ---- phase 0: stage weights, scatter W, load X ----
    for (int i = t; i < HIDP * 8; i += 1024) {
        const int c = i >> 3, k = i & 7;
        float v = 0.f;
        if (c < HID) {
            if (k < FIN) v = lin_w[k * HID + c];
            else if (k == FIN) v = lin_b[c];
        }
        lwT[c][k] = f2bf(v);
    }
    for (int i = t; i < HIDP * 2; i += 1024) fcs[i] = (i < HID * 2) ? fc_w[i] : 0.f;
    if (t < 8) Zs[t] = 0;
    for (int e = t; e < NTRIL; e += 1024) {
        const int x = tx[e], y = ty[e];
        const float v = ew[e];
        Wn[x * MST + y] = v;
        Wn[y * MST + x] = v;
    }
    bf16x8 bx0 = {}, bx1 = {};
    if (b < B) {
        const float* xb = X + (size_t)b * (NNODE * FIN);
        for (int idx = lane; idx < NNODE * FIN; idx += 64) {
            const int n = idx / FIN, f = idx - n * FIN;
            XT[w][f][n] = f2bf(xb[idx]);
        }
        if (lane < FIN) *(unsigned int*)&XT[w][lane][62] = 0u;   // node pads 62,63
        // EARLY hop-1 B-frag load: same-wave RAW on XT is in-order, no barrier
        // needed; masked lanes use a register zero (Zs not yet synced here).
        const int fc16 = fr ? f16 : 0;
        const bf16x8 e0 = *(const bf16x8*)&XT[w][fc16][g * 8];
        const bf16x8 e1 = *(const bf16x8*)&XT[w][fc16][32 + g * 8];
        if (fr) { bx0 = e0; bx1 = e1; }
    }
    __syncthreads();

    // ---- phase 1: row degrees -> D^-1/2 (16 threads per row) ----
    if (t < NNODE * 16) {
        const int r = t >> 4, j = t & 15;
        float s = 0.f;
        for (int k = j; k < NNODE; k += 16) s += fabsf(Wn[r * MST + k]);
        s += __shfl_xor(s, 8);
        s += __shfl_xor(s, 4);
        s += __shfl_xor(s, 2);
        s += __shfl_xor(s, 1);
        if (j == 0) dinv[r] = (s > 0.f) ? (1.0f / sqrtf(s)) : 0.f;
    }
    __syncthreads();

    // ---- phase 2: normalize + convert into 16x16 A-frag order (threads 0-511) ----
    if (t < 512) {
        const int fi = t >> 6, l = t & 63;           // fi = rt*2 + ks
        const int rt = fi >> 1, ks = fi & 1;
        const int row = (l & 15) + 16 * rt;
        const int k0 = ks * 32 + (l >> 4) * 8;
        union { short s[8]; bf16x8 v8; } u;
        #pragma unroll
        for (int j = 0; j < 8; ++j) {
            const int k = k0 + j;
            u.s[j] = (row < NNODE && k < NNODE)
                   ? f2bf(Wn[row * MST + k] * dinv[row] * dinv[k]) : (short)0;
        }
        *(bf16x8*)&Wfrag[fi][l][0] = u.v8;
    }
    __syncthreads();    // last block-wide barrier

    if (b >= B) return;

    // ---- per-wave: cache W A-frags in VGPRs ----
    bf16x8 wf[8];
    #pragma unroll
    for (int fi = 0; fi < 8; ++fi) wf[fi] = *(const bf16x8*)&Wfrag[fi][lane][0];

    const short* zp = &Zs[0];
    const f32x4 z4 = {0.f, 0.f, 0.f, 0.f};

    // hop 1: Y1 = Wn @ X  (bx0/bx1 loaded pre-barrier)
    f32x4 acc[4];
    __builtin_amdgcn_s_setprio(1);
    #pragma unroll
    for (int rt = 0; rt < 4; ++rt) {
        acc[rt] = __builtin_amdgcn_mfma_f32_16x16x32_bf16(wf[rt * 2 + 0], bx0, z4, 0, 0, 0);
        acc[rt] = __builtin_amdgcn_mfma_f32_16x16x32_bf16(wf[rt * 2 + 1], bx1, acc[rt], 0, 0, 0);
    }
    __builtin_amdgcn_s_setprio(0);
    if (fr) {   // Y1^T writeback (same-wave in-order LDS)
        #pragma unroll
        for (int rt = 0; rt < 4; ++rt) {
            const int n0 = rt * 16 + g * 4;          // D row = (lane>>4)*4 + reg (+16rt)
            const unsigned int d0 = (unsigned short)f2bf(acc[rt][0]) |
                                    ((unsigned int)(unsigned short)f2bf(acc[rt][1]) << 16);
            const unsigned int d1 = (unsigned short)f2bf(acc[rt][2]) |
                                    ((unsigned int)(unsigned short)f2bf(acc[rt][3]) << 16);
            if (n0 + 1 < NNODE) *(unsigned int*)&XT[w][f16][n0] = d0;
            if (n0 + 3 < NNODE) *(unsigned int*)&XT[w][f16][n0 + 2] = d1;
        }
    }

    // hop 2: Y2 = Wn @ Y1
    {
        const short* p0 = fr ? &XT[w][f16][g * 8]      : zp;
        const short* p1 = fr ? &XT[w][f16][32 + g * 8] : zp;
        bx0 = *(const bf16x8*)p0;
        bx1 = *(const bf16x8*)p1;
    }
    __builtin_amdgcn_s_setprio(1);
    #pragma unroll
    for (int rt = 0; rt < 4; ++rt) {
        acc[rt] = __builtin_amdgcn_mfma_f32_16x16x32_bf16(wf[rt * 2 + 0], bx0, z4, 0, 0, 0);
        acc[rt] = __builtin_amdgcn_mfma_f32_16x16x32_bf16(wf[rt * 2 + 1], bx1, acc[rt], 0, 0, 0);
    }
    __builtin_amdgcn_s_setprio(0);
    // scatter Y2 with FULL Y2A coverage: lanes f16<8 write k=0..7
    if (f16 < 8) {
        #pragma unroll
        for (int rt = 0; rt < 4; ++rt) {
            const int n0 = rt * 16 + g * 4;
            #pragma unroll
            for (int r = 0; r < 4; ++r) {
                const int n = n0 + r;
                short val = 0;
                if (n < NNODE) {
                    val = (f16 < FIN) ? f2bf(acc[rt][r])
                                      : ((f16 == FIN) ? (short)0x3F80 : (short)0);
                }
                Y2A[w][n][f16] = val;
            }
        }
    }

    // ---- lin stage (32x32x16): A rows = Y2A nodes; lanes 0-31 carry k=0..7 ----
    const int r32 = lane & 31;
    const bool alo = (lane < 32);
    bf16x8 af0, af1;
    {
        const short* a0 = alo ? &Y2A[w][r32][0]      : zp;
        const short* a1 = alo ? &Y2A[w][32 + r32][0] : zp;
        af0 = *(const bf16x8*)a0;
        af1 = *(const bf16x8*)a1;
    }

    // 13 col-tiles, 2-deep software pipeline: issue tile ct+1's MFMAs before
    // reducing tile ct (MFMA pipe fills while the VALU hsum chain drains).
    const f32x16 z16 = {};
    float o0 = 0.f, o1 = 0.f;
    bf16x8 bfr[2];
    float2 fw[2];
    f32x16 da[2], db[2];
    {
        const short* bp = alo ? &lwT[r32][0] : zp;
        bfr[0] = *(const bf16x8*)bp;
        fw[0]  = *(const float2*)&fcs[r32 * 2];
    }
    __builtin_amdgcn_s_setprio(1);
    da[0] = __builtin_amdgcn_mfma_f32_32x32x16_bf16(af0, bfr[0], z16, 0, 0, 0);
    db[0] = __builtin_amdgcn_mfma_f32_32x32x16_bf16(af1, bfr[0], z16, 0, 0, 0);
    __builtin_amdgcn_s_setprio(0);
    #pragma unroll
    for (int ct = 0; ct < 13; ++ct) {
        const int cur = ct & 1, nxt = cur ^ 1;
        if (ct < 12) {
            const short* bp = alo ? &lwT[32 * (ct + 1) + r32][0] : zp;
            bfr[nxt] = *(const bf16x8*)bp;
            fw[nxt]  = *(const float2*)&fcs[(32 * (ct + 1) + r32) * 2];
            __builtin_amdgcn_s_setprio(1);
            da[nxt] = __builtin_amdgcn_mfma_f32_32x32x16_bf16(af0, bfr[nxt], z16, 0, 0, 0);
            db[nxt] = __builtin_amdgcn_mfma_f32_32x32x16_bf16(af1, bfr[nxt], z16, 0, 0, 0);
            __builtin_amdgcn_s_setprio(0);
        }
        const float pc = hsum16_relu(da[cur]) + hsum16_relu(db[cur]);
        o0 = fmaf(pc, fw[cur].x, o0);
        o1 = fmaf(pc, fw[cur].y, o1);
    }

    // one full-wave butterfly over (row-half, col) partials
    #pragma unroll
    for (int s = 32; s > 0; s >>= 1) {
        o0 += __shfl_xor(o0, s, 64);
        o1 += __shfl_xor(o1, s, 64);
    }
    if (lane == 0) {
        out[2 * b + 0] = o0 + fc_b[0];
        out[2 * b + 1] = o1 + fc_b[1];
    }
}

extern "C" void kernel_launch(void* const* d_in, const int* in_sizes, int n_in,
                              void* d_out, int out_size, void* d_ws, size_t ws_size,
                              hipStream_t stream) {
    const float* X     = (const float*)d_in[0];
    const float* ew    = (const float*)d_in[2];
    const float* lin_w = (const float*)d_in[3];
    const float* lin_b = (const float*)d_in[4];
    const float* fc_w  = (const float*)d_in[5];
    const float* fc_b  = (const float*)d_in[6];
    const int*   tx    = (const int*)d_in[9];
    const int*   ty    = (const int*)d_in[10];

    float* outp = (float*)d_out;
    const int B = in_sizes[0] / (NNODE * FIN);   // 4096

    rgnn_fused<<<(B + WAVES - 1) / WAVES, 1024, 0, stream>>>(
        X, ew, tx, ty, lin_w, lin_b, fc_w, fc_b, outp, B);
}